// Round 2
// baseline (967.524 us; speedup 1.0000x reference)
//
#include <hip/hip_runtime.h>
#include <hip/hip_bf16.h>

#define HID 100
#define TT 750
#define NB_TOT 1024
#define ALPHA 0.01f
#define NSTD 0.1f

typedef __bf16 bf16x8 __attribute__((ext_vector_type(8)));
typedef float floatx4 __attribute__((ext_vector_type(4)));

__device__ __forceinline__ float fast_tanh(float v) {
    // tanh(v) = 1 - 2/(exp(2v)+1); graceful at +-inf, abs err ~1e-6
    float e = __expf(2.0f * v);
    return 1.0f - 2.0f / (e + 1.0f);
}

// Workgroup barrier WITHOUT the vmcnt(0) drain __syncthreads() emits:
// lgkmcnt(0) makes our ds ops visible; global prefetch stays in flight.
__device__ __forceinline__ void wg_barrier() {
    asm volatile("s_waitcnt lgkmcnt(0)" ::: "memory");
    __builtin_amdgcn_s_barrier();
    asm volatile("" ::: "memory");
    __builtin_amdgcn_sched_barrier(0);
}

struct Pf {
    float n00, n01, n10, n11;   // noise [tile][batch]
    floatx4 u0, u1;             // input row [batch]
};

__global__ __launch_bounds__(256, 2)
void rnn_kernel(const float* __restrict__ useq,   // [750][1024][4]
                const float* __restrict__ noise,  // [750][1024][100]
                const float* __restrict__ Jw,     // [100][100]
                const float* __restrict__ Bm,     // [4][100]
                const float* __restrict__ cxp,    // [100]
                const float* __restrict__ Ww,     // [100]
                const float* __restrict__ Wb,     // [1]
                float* __restrict__ out)          // [1024]
{
    // DOUBLE-buffered r: 2 x (16 rows M x 128 bf16 K), 16B-chunk XOR swizzle.
    // Double buffering makes ONE barrier per step sufficient (writes of step t
    // go to buf[p^1] while slow waves may still read buf[p]).
    __shared__ __align__(16) __bf16 rbuf[2][16 * 128];
    __shared__ float red[2][112];

    const int tid  = threadIdx.x;
    const int wv   = tid >> 6;
    const int lane = tid & 63;
    const int wg   = blockIdx.x;
    const int m16  = lane & 15;
    const int q    = lane >> 4;

    const int gb0 = wg * 2 + 0;
    const int gb1 = wg * 2 + 1;

    // C-layout update mapping: wave wv computes N-tiles {2wv, 2wv+1}; after
    // MFMA, lanes 0..15 hold y[hh = tile*16+lane] for batch 0 in reg 0 and
    // batch 1 in reg 1. The x-update happens RIGHT THERE, in registers.
    const int  hh0 = (wv * 2 + 0) * 16 + m16;
    const int  hh1 = (wv * 2 + 1) * 16 + m16;
    const bool act = (q == 0);
    const bool v0  = act && (hh0 < HID);
    const bool v1  = act && (hh1 < HID);
    const int  h0c = (hh0 < HID) ? hh0 : 0;   // clamped (avoid OOB loads)
    const int  h1c = (hh1 < HID) ? hh1 : 0;

    floatx4 bmA = {0,0,0,0}, bmB = {0,0,0,0};
    float cx0 = 0.f, cx1 = 0.f, w0 = 0.f, w1 = 0.f;
    if (v0) {
        bmA = floatx4{Bm[0*HID+hh0], Bm[1*HID+hh0], Bm[2*HID+hh0], Bm[3*HID+hh0]};
        cx0 = cxp[hh0]; w0 = Ww[hh0];
    }
    if (v1) {
        bmB = floatx4{Bm[0*HID+hh1], Bm[1*HID+hh1], Bm[2*HID+hh1], Bm[3*HID+hh1]};
        cx1 = cxp[hh1]; w1 = Ww[hh1];
    }

    // zero BOTH r buffers (rows 2..15, k>=100 stay zero forever; r_0 = 0)
    {
        floatx4 z = {0.f, 0.f, 0.f, 0.f};
        ((floatx4*)rbuf)[tid]       = z;
        ((floatx4*)rbuf)[tid + 256] = z;
    }

    // --- preload J fragments (B-operand layout), split hi/lo bf16 ---
    bf16x8 jhi[2][4], jlo[2][4];
    #pragma unroll
    for (int ti = 0; ti < 2; ++ti) {
        const int tile = wv * 2 + ti;
        const int h = tile * 16 + m16;     // B n-index -> J row h
        #pragma unroll
        for (int s = 0; s < 4; ++s) {
            bf16x8 vhi, vlo;
            #pragma unroll
            for (int j = 0; j < 8; ++j) {
                const int k = s * 32 + q * 8 + j;
                float v = (h < HID && k < HID) ? Jw[h * HID + k] : 0.0f;
                __bf16 hi = (__bf16)v;
                vhi[j] = hi;
                vlo[j] = (__bf16)(v - (float)hi);
            }
            jhi[ti][s] = vhi;
            jlo[ti][s] = vlo;
        }
    }

    // swizzled rbuf write offsets (elements): row=batch, chunk ^= batch
    const int a00 = hh0;               // batch 0, col hh0 (chunk^0 == identity)
    const int a01 = 128 + (hh0 ^ 8);   // batch 1, col hh0
    const int a10 = hh1;
    const int a11 = 128 + (hh1 ^ 8);

    // --- prefetch pipeline (depth 4) for noise + input, C-layout lanes ---
    const float* np00 = noise + (size_t)gb0 * HID + h0c;
    const float* np01 = noise + (size_t)gb1 * HID + h0c;
    const float* np10 = noise + (size_t)gb0 * HID + h1c;
    const float* np11 = noise + (size_t)gb1 * HID + h1c;
    const float* up0  = useq  + (size_t)gb0 * 4;
    const float* up1  = useq  + (size_t)gb1 * 4;

    auto pfetch = [&](int t, Pf& P) {
        if (act) {
            const size_t tn = (size_t)t * (NB_TOT * HID);
            const size_t tu = (size_t)t * (NB_TOT * 4);
            P.n00 = np00[tn]; P.n01 = np01[tn];
            P.n10 = np10[tn]; P.n11 = np11[tn];
            P.u0 = *(const floatx4*)(up0 + tu);
            P.u1 = *(const floatx4*)(up1 + tu);
        }
    };

    Pf p0, p1, p2, p3;
    pfetch(0, p0); pfetch(1, p1); pfetch(2, p2); pfetch(3, p3);

    float x00 = 0.f, x01 = 0.f, x10 = 0.f, x11 = 0.f;
    __syncthreads();   // once before the loop

    auto step = [&](int T, Pf& P, int pb) {
        // ---- A-frags from rbuf[pb] ----
        bf16x8 afr[4];
        const bf16x8* rb16 = (const bf16x8*)(rbuf[pb]);
        #pragma unroll
        for (int s = 0; s < 4; ++s)
            afr[s] = rb16[m16 * 16 + ((s * 4 + q) ^ (lane & 7))];
        // ---- MFMA: dual 4-deep hi/lo chains per tile ----
        float y00, y01, y10, y11;
        {
            floatx4 acch = {0,0,0,0}, accl = {0,0,0,0};
            #pragma unroll
            for (int s = 0; s < 4; ++s) {
                acch = __builtin_amdgcn_mfma_f32_16x16x32_bf16(afr[s], jhi[0][s], acch, 0, 0, 0);
                accl = __builtin_amdgcn_mfma_f32_16x16x32_bf16(afr[s], jlo[0][s], accl, 0, 0, 0);
            }
            y00 = acch[0] + accl[0]; y01 = acch[1] + accl[1];
        }
        {
            floatx4 acch = {0,0,0,0}, accl = {0,0,0,0};
            #pragma unroll
            for (int s = 0; s < 4; ++s) {
                acch = __builtin_amdgcn_mfma_f32_16x16x32_bf16(afr[s], jhi[1][s], acch, 0, 0, 0);
                accl = __builtin_amdgcn_mfma_f32_16x16x32_bf16(afr[s], jlo[1][s], accl, 0, 0, 0);
            }
            y10 = acch[0] + accl[0]; y11 = acch[1] + accl[1];
        }
        // ---- in-register update + r write into rbuf[pb^1] ----
        __bf16* wb = rbuf[pb ^ 1];
        if (act) {
            if (v0) {
                const float d0 = P.u0[0]*bmA[0] + P.u0[1]*bmA[1] + P.u0[2]*bmA[2] + P.u0[3]*bmA[3];
                x00 = x00 * (1.0f - ALPHA) + ALPHA * (y00 + d0 + cx0 + NSTD * P.n00);
                wb[a00] = (__bf16)fast_tanh(x00);
                const float d1 = P.u1[0]*bmA[0] + P.u1[1]*bmA[1] + P.u1[2]*bmA[2] + P.u1[3]*bmA[3];
                x01 = x01 * (1.0f - ALPHA) + ALPHA * (y01 + d1 + cx0 + NSTD * P.n01);
                wb[a01] = (__bf16)fast_tanh(x01);
            }
            if (v1) {
                const float d0 = P.u0[0]*bmB[0] + P.u0[1]*bmB[1] + P.u0[2]*bmB[2] + P.u0[3]*bmB[3];
                x10 = x10 * (1.0f - ALPHA) + ALPHA * (y10 + d0 + cx1 + NSTD * P.n10);
                wb[a10] = (__bf16)fast_tanh(x10);
                const float d1 = P.u1[0]*bmB[0] + P.u1[1]*bmB[1] + P.u1[2]*bmB[2] + P.u1[3]*bmB[3];
                x11 = x11 * (1.0f - ALPHA) + ALPHA * (y11 + d1 + cx1 + NSTD * P.n11);
                wb[a11] = (__bf16)fast_tanh(x11);
            }
            // prefetch t+4 (stays in flight across wg_barrier)
            const int tf = (T + 4 < TT) ? (T + 4) : (TT - 1);
            const size_t tn = (size_t)tf * (NB_TOT * HID);
            const size_t tu = (size_t)tf * (NB_TOT * 4);
            P.n00 = np00[tn]; P.n01 = np01[tn];
            P.n10 = np10[tn]; P.n11 = np11[tn];
            P.u0 = *(const floatx4*)(up0 + tu);
            P.u1 = *(const floatx4*)(up1 + tu);
        }
        wg_barrier();   // ONE barrier per step
    };

    for (int tb = 0; tb < 748; tb += 4) {
        step(tb + 0, p0, 0);
        step(tb + 1, p1, 1);
        step(tb + 2, p2, 0);
        step(tb + 3, p3, 1);
    }
    step(748, p0, 0);
    step(749, p1, 1);

    // ---- epilogue: out[b] = sum_h tanh(x_final)*Wout[h] + Wout_b ----
    if (v0) { red[0][hh0] = fast_tanh(x00) * w0; red[1][hh0] = fast_tanh(x01) * w0; }
    if (v1) { red[0][hh1] = fast_tanh(x10) * w1; red[1][hh1] = fast_tanh(x11) * w1; }
    __syncthreads();
    if (tid < 2) {
        float s2 = Wb[0];
        #pragma unroll 4
        for (int i = 0; i < HID; ++i) s2 += red[tid][i];
        out[wg * 2 + tid] = s2;
    }
}

extern "C" void kernel_launch(void* const* d_in, const int* in_sizes, int n_in,
                              void* d_out, int out_size, void* d_ws, size_t ws_size,
                              hipStream_t stream) {
    rnn_kernel<<<dim3(512), dim3(256), 0, stream>>>(
        (const float*)d_in[0], (const float*)d_in[1], (const float*)d_in[2],
        (const float*)d_in[3], (const float*)d_in[4], (const float*)d_in[5],
        (const float*)d_in[6], (float*)d_out);
}